// Round 15
// baseline (141.956 us; speedup 1.0000x reference)
//
#include <hip/hip_runtime.h>
#include <hip/hip_bf16.h>
#include <cstdint>
#include <cstddef>

#define NN 8192
#define FIN 256
#define FO 128
#define SPLITK 8
#define JCH 1024   // NN / SPLITK; 16 bodies x 64 j; 4 windows x 256 j

typedef float f32x4 __attribute__((ext_vector_type(4)));
typedef _Float16 f16x8 __attribute__((ext_vector_type(8)));
typedef unsigned long long ull;

typedef __attribute__((address_space(3))) void lds_void;
typedef const __attribute__((address_space(1))) void glb_void;
__device__ __forceinline__ void gl_lds16(const void* g, void* l) {
  __builtin_amdgcn_global_load_lds((glb_void*)g, (lds_void*)l, 16, 0, 0);
}

__device__ __forceinline__ unsigned enc_f32(float f) {
  unsigned u = __float_as_uint(f);
  return (u & 0x80000000u) ? ~u : (u | 0x80000000u);
}
__device__ __forceinline__ float dec_f32(unsigned u) {
  unsigned b = (u & 0x80000000u) ? (u ^ 0x80000000u) : ~u;
  return __uint_as_float(b);
}

// ---------------- K1: h = x @ W  (8192x256 @ 256x128) ----------------
__global__ void k1_xw(const float* __restrict__ x, const float* __restrict__ W,
                      float* __restrict__ h, unsigned* __restrict__ enc) {
  __shared__ float xs[32 * 66];
  __shared__ float Ws[64 * 128];
  int t = threadIdx.x;
  int r0 = blockIdx.x * 32;
  if (blockIdx.x == 0 && t == 0) *enc = 0u;  // init for K2's atomicMax
  int r = t & 31, cg = t >> 5;
  float acc[16];
#pragma unroll
  for (int i = 0; i < 16; ++i) acc[i] = 0.f;
  for (int ko = 0; ko < 4; ++ko) {
    __syncthreads();
    {
      int rr = t >> 3, kc = (t & 7) * 8;
      const float2* src = (const float2*)(x + (size_t)(r0 + rr) * FIN + ko * 64 + kc);
      float2* dst = (float2*)&xs[rr * 66 + kc];
#pragma unroll
      for (int q = 0; q < 4; ++q) dst[q] = src[q];
    }
    {
      int kk = t >> 2, q = t & 3;
      const float4* src = (const float4*)(W + (size_t)(ko * 64 + kk) * FO + q * 32);
      float4* dst = (float4*)&Ws[kk * 128 + q * 32];
#pragma unroll
      for (int i = 0; i < 8; ++i) dst[i] = src[i];
    }
    __syncthreads();
#pragma unroll 8
    for (int kk = 0; kk < 64; ++kk) {
      float xv = xs[r * 66 + kk];
      const float4* wr = (const float4*)&Ws[kk * 128 + cg * 16];
      float4 w0 = wr[0], w1 = wr[1], w2 = wr[2], w3 = wr[3];
      acc[0]  = fmaf(xv, w0.x, acc[0]);  acc[1]  = fmaf(xv, w0.y, acc[1]);
      acc[2]  = fmaf(xv, w0.z, acc[2]);  acc[3]  = fmaf(xv, w0.w, acc[3]);
      acc[4]  = fmaf(xv, w1.x, acc[4]);  acc[5]  = fmaf(xv, w1.y, acc[5]);
      acc[6]  = fmaf(xv, w1.z, acc[6]);  acc[7]  = fmaf(xv, w1.w, acc[7]);
      acc[8]  = fmaf(xv, w2.x, acc[8]);  acc[9]  = fmaf(xv, w2.y, acc[9]);
      acc[10] = fmaf(xv, w2.z, acc[10]); acc[11] = fmaf(xv, w2.w, acc[11]);
      acc[12] = fmaf(xv, w3.x, acc[12]); acc[13] = fmaf(xv, w3.y, acc[13]);
      acc[14] = fmaf(xv, w3.z, acc[14]); acc[15] = fmaf(xv, w3.w, acc[15]);
    }
  }
  float* hp = h + (size_t)(r0 + r) * FO + cg * 16;
#pragma unroll
  for (int i = 0; i < 4; ++i)
    ((float4*)hp)[i] = make_float4(acc[4 * i], acc[4 * i + 1], acc[4 * i + 2], acc[4 * i + 3]);
}

// ---------------- K2: hT (fp16 transpose), s1, s2, max(s2) ----------------
__global__ void k2_prep(const float* __restrict__ h, const float* __restrict__ a,
                        _Float16* __restrict__ hT,
                        float* __restrict__ s1, float* __restrict__ s2,
                        unsigned* __restrict__ enc) {
  __shared__ float ht[64 * 129];
  int t = threadIdx.x;
  int r0 = blockIdx.x * 64;
  {
    int rr = t >> 2, q = t & 3;
    const float4* src = (const float4*)(h + (size_t)(r0 + rr) * FO + q * 32);
    float* dst = &ht[rr * 129 + q * 32];
#pragma unroll
    for (int i = 0; i < 8; ++i) {
      float4 v = src[i];
      dst[4 * i + 0] = v.x; dst[4 * i + 1] = v.y;
      dst[4 * i + 2] = v.z; dst[4 * i + 3] = v.w;
    }
  }
  __syncthreads();
  {
    int c = t >> 1, half = t & 1;
    alignas(16) _Float16 buf[32];
#pragma unroll
    for (int i = 0; i < 32; ++i) buf[i] = (_Float16)ht[(half * 32 + i) * 129 + c];
    int4* d = (int4*)(hT + (size_t)c * NN + r0 + half * 32);
#pragma unroll
    for (int i = 0; i < 4; ++i) d[i] = ((const int4*)buf)[i];
  }
  if (t < 64) {
    int row = r0 + t;
    float v1 = 0.f, v2 = 0.f;
#pragma unroll 16
    for (int c = 0; c < FO; ++c) {
      float hv = ht[t * 129 + c];
      v1 = fmaf(hv, a[c], v1);
      v2 = fmaf(hv, a[FO + c], v2);
    }
    s1[row] = v1; s2[row] = v2;
    float m = v2;
#pragma unroll
    for (int off = 1; off < 64; off <<= 1) m = fmaxf(m, __shfl_xor(m, off));
    if (t == 0) atomicMax(enc, enc_f32(m));
  }
}

// weight: w = bit ? exp(leaky(s1+s2) - m) : 0, rounded to fp16;
// den accumulates the *rounded* weight in f32 for exact normalization consistency.
__device__ __forceinline__ _Float16 wel(unsigned av, float s2v, float s1v, float mv, float& sum) {
  float tt = s1v + s2v;
  tt = fmaxf(tt, 0.01f * tt);  // leaky_relu
  float wf = av ? __expf(tt - mv) : 0.f;
  _Float16 wh = (_Float16)wf;
  sum += (float)wh;
  return wh;
}

// Load 4 rows (4P..4P+3) of a 256-col window: ONE int4/row = 1 KB contiguous
// per wave-instruction (page-burst: each 4KB row-page consumed in 4 sweeps).
#define LOAD4(SET, WIN, P)                                                       \
  _Pragma("unroll")                                                              \
  for (int rr = 0; rr < 4; ++rr)                                                 \
    SET[rr] = *(const int4*)(abase + (size_t)(4 * (P) + rr) * NN +               \
                             jbeg + (WIN) * 256);

// Ballot a loaded 4-row set into the window mask group (pre-shifted by kgrp*2).
// (bit plumbing hardware-verified: r13 passed with this exact mapping)
#define BAL4(SET, P, M0, M1, M2, M3)                                             \
  _Pragma("unroll")                                                              \
  for (int rr = 0; rr < 4; ++rr) {                                               \
    ull b0 = __ballot(SET[rr].x > 0);                                            \
    ull b1 = __ballot(SET[rr].y > 0);                                            \
    ull b2 = __ballot(SET[rr].z > 0);                                            \
    ull b3 = __ballot(SET[rr].w > 0);                                            \
    bool sel = (l15 == 4 * (P) + rr);                                            \
    M0 = sel ? (b0 >> sh2) : M0;                                                 \
    M1 = sel ? (b1 >> sh2) : M1;                                                 \
    M2 = sel ? (b2 >> sh2) : M2;                                                 \
    M3 = sel ? (b3 >> sh2) : M3;                                                 \
  }

// One body (64 j): af[e] <-> word e&3, bit (T&3)*16 + ks*8 + e/4.
#define CONS(M0, M1, M2, M3, T)                                                  \
  {                                                                              \
    _Pragma("unroll")                                                            \
    for (int ks = 0; ks < 2; ++ks) {                                             \
      int SH = ((T) & 3) * 16 + ks * 8;                                          \
      unsigned c0 = (unsigned)((M0) >> SH);                                      \
      unsigned c1 = (unsigned)((M1) >> SH);                                      \
      unsigned c2 = (unsigned)((M2) >> SH);                                      \
      unsigned c3 = (unsigned)((M3) >> SH);                                      \
      int jloc = (T) * 64 + ks * 32 + kgrp * 8;                                  \
      f32x4 sa = *(const f32x4*)&s2l[jloc];                                      \
      f32x4 sb = *(const f32x4*)&s2l[jloc + 4];                                  \
      f16x8 af;                                                                  \
      af[0] = wel(c0 & 1u, sa[0], s10, mx0, sum0);                               \
      af[1] = wel(c1 & 1u, sa[1], s10, mx0, sum0);                               \
      af[2] = wel(c2 & 1u, sa[2], s10, mx0, sum0);                               \
      af[3] = wel(c3 & 1u, sa[3], s10, mx0, sum0);                               \
      af[4] = wel(c0 & 2u, sb[0], s10, mx0, sum0);                               \
      af[5] = wel(c1 & 2u, sb[1], s10, mx0, sum0);                               \
      af[6] = wel(c2 & 2u, sb[2], s10, mx0, sum0);                               \
      af[7] = wel(c3 & 2u, sb[3], s10, mx0, sum0);                               \
      _Pragma("unroll")                                                          \
      for (int cf = 0; cf < 8; ++cf) {                                           \
        f16x8 bfr = *(const f16x8*)&tile[(T) & 1][(cf * 16 + l15) * 64 +         \
                       ((ks * 32 + kgrp * 8) ^ (l7 * 8))];                       \
        acc[cf] = __builtin_amdgcn_mfma_f32_16x16x32_f16(af, bfr, acc[cf], 0, 0, 0); \
      }                                                                          \
    }                                                                            \
  }

// Body T: stage next tile; ballot S (set loaded at T-1; implicit vmcnt(4) wait
// keeps the just-issued stage in flight); reload S (same regs) for the next
// set; compute; end vmcnt(4) retires the stage (tile ready), keeps S.
#define BODY(T, DOB, PB, DOL, LW, LQ, C0, C1, C2, C3, B0, B1, B2, B3, VMS)       \
  {                                                                              \
    if ((T) < 15) stage(((T) + 1) & 1, jbeg + ((T) + 1) * 64);                   \
    if (DOB) { BAL4(S, PB, B0, B1, B2, B3) }                                     \
    if (DOL) { LOAD4(S, LW, LQ) }                                                \
    __builtin_amdgcn_sched_barrier(0);                                           \
    CONS(C0, C1, C2, C3, T)                                                      \
    __builtin_amdgcn_sched_barrier(0);                                           \
    if ((T) < 15) {                                                              \
      asm volatile("s_waitcnt vmcnt(" VMS ")" ::: "memory");                     \
      __builtin_amdgcn_s_barrier();                                              \
      __builtin_amdgcn_sched_barrier(0);                                         \
    }                                                                            \
  }

// ---------------- K4: fused attention x h, PAGE-BURST adj (single-S) ---------
// r14 chassis (grid (8,128), 4 waves x 16 rows, swizzled [128][64] fp16 tile
// dbuf, counted vmcnt, one barrier/body, fp16 num_p) with adj read as 4 rows
// x 1 KB per body. SINGLE S[4] buffer (ballot-then-reload) keeps the adj
// register state at 32 regs = r6-equal (r13's spill fixed). Masks Ma/Mb
// double-buffered by window parity; window W fully balloted by body 4W.
__global__ void __launch_bounds__(256, 4) k4_main(
    const int* __restrict__ adj, const float* __restrict__ s1g,
    const float* __restrict__ s2g, const unsigned* __restrict__ enc,
    const _Float16* __restrict__ hT,
    _Float16* __restrict__ num_p, float* __restrict__ den_p) {
  __shared__ _Float16 tile[2][128 * 64];
  __shared__ float s2l[JCH];
  int t = threadIdx.x;
  int l = t & 63, wv = t >> 6;
  int l15 = l & 15, kgrp = l >> 4;
  int l7 = l15 & 7;
  int sh2 = kgrp * 2;
  int split = blockIdx.x;
  int r0 = blockIdx.y * 64;
  int jbeg = split * JCH;
  int row = r0 + wv * 16 + l15;

  float c2 = dec_f32(*enc);
  float s10 = s1g[row];
  float mx0 = s10 + c2; mx0 = fmaxf(mx0, 0.01f * mx0);

  f32x4 acc[8];
#pragma unroll
  for (int cf = 0; cf < 8; ++cf) acc[cf] = (f32x4){0.f, 0.f, 0.f, 0.f};
  float sum0 = 0.f;
  const int* abase = adj + (size_t)(r0 + wv * 16) * NN + 4 * l;  // lane's 16B slot

  auto stage = [&](int b, int jg) {
    const _Float16* g0 = hT + (size_t)(wv * 32 + (l >> 3)) * NN + jg +
                         (((l & 7) ^ (l >> 3)) * 8);
    _Float16* base = &tile[b][(wv * 32) * 64];
    gl_lds16(g0, base);
    gl_lds16(g0 + (size_t)8 * NN, base + 8 * 64);
    gl_lds16(g0 + (size_t)16 * NN, base + 16 * 64);
    gl_lds16(g0 + (size_t)24 * NN, base + 24 * 64);
  };

  int4 S[4];
  ull Ma0 = 0, Ma1 = 0, Ma2 = 0, Ma3 = 0;   // masks, even-parity window
  ull Mb0 = 0, Mb1 = 0, Mb2 = 0, Mb3 = 0;   // masks, odd-parity window

  // ---- prologue: s2 slice, tile0, window-0 masks (sequential), preload set0/win1
  *(float4*)&s2l[t * 4] = *(const float4*)(s2g + jbeg + t * 4);
  stage(0, jbeg);
  LOAD4(S, 0, 0) BAL4(S, 0, Ma0, Ma1, Ma2, Ma3)
  LOAD4(S, 0, 1) BAL4(S, 1, Ma0, Ma1, Ma2, Ma3)
  LOAD4(S, 0, 2) BAL4(S, 2, Ma0, Ma1, Ma2, Ma3)
  LOAD4(S, 0, 3) BAL4(S, 3, Ma0, Ma1, Ma2, Ma3)
  LOAD4(S, 1, 0)
  asm volatile("s_waitcnt vmcnt(4) lgkmcnt(0)" ::: "memory");
  __builtin_amdgcn_s_barrier();
  __builtin_amdgcn_sched_barrier(0);

  // ---- 16 bodies, fully static. window w consumed at bodies 4w..4w+3;
  //      set q of window w+1 balloted at body 4w+q (loaded one body earlier).
  BODY(0,  1, 0, 1, 1, 1, Ma0, Ma1, Ma2, Ma3, Mb0, Mb1, Mb2, Mb3, "4")
  BODY(1,  1, 1, 1, 1, 2, Ma0, Ma1, Ma2, Ma3, Mb0, Mb1, Mb2, Mb3, "4")
  BODY(2,  1, 2, 1, 1, 3, Ma0, Ma1, Ma2, Ma3, Mb0, Mb1, Mb2, Mb3, "4")
  BODY(3,  1, 3, 1, 2, 0, Ma0, Ma1, Ma2, Ma3, Mb0, Mb1, Mb2, Mb3, "4")
  BODY(4,  1, 0, 1, 2, 1, Mb0, Mb1, Mb2, Mb3, Ma0, Ma1, Ma2, Ma3, "4")
  BODY(5,  1, 1, 1, 2, 2, Mb0, Mb1, Mb2, Mb3, Ma0, Ma1, Ma2, Ma3, "4")
  BODY(6,  1, 2, 1, 2, 3, Mb0, Mb1, Mb2, Mb3, Ma0, Ma1, Ma2, Ma3, "4")
  BODY(7,  1, 3, 1, 3, 0, Mb0, Mb1, Mb2, Mb3, Ma0, Ma1, Ma2, Ma3, "4")
  BODY(8,  1, 0, 1, 3, 1, Ma0, Ma1, Ma2, Ma3, Mb0, Mb1, Mb2, Mb3, "4")
  BODY(9,  1, 1, 1, 3, 2, Ma0, Ma1, Ma2, Ma3, Mb0, Mb1, Mb2, Mb3, "4")
  BODY(10, 1, 2, 1, 3, 3, Ma0, Ma1, Ma2, Ma3, Mb0, Mb1, Mb2, Mb3, "4")
  BODY(11, 1, 3, 0, 3, 0, Ma0, Ma1, Ma2, Ma3, Mb0, Mb1, Mb2, Mb3, "0")
  BODY(12, 0, 0, 0, 3, 0, Mb0, Mb1, Mb2, Mb3, Ma0, Ma1, Ma2, Ma3, "0")
  BODY(13, 0, 0, 0, 3, 0, Mb0, Mb1, Mb2, Mb3, Ma0, Ma1, Ma2, Ma3, "0")
  BODY(14, 0, 0, 0, 3, 0, Mb0, Mb1, Mb2, Mb3, Ma0, Ma1, Ma2, Ma3, "0")
  BODY(15, 0, 0, 0, 3, 0, Mb0, Mb1, Mb2, Mb3, Ma0, Ma1, Ma2, Ma3, "0")

  // row sums: lanes kgrp 0..3 of same l15 combine
  sum0 += __shfl_xor(sum0, 16);
  sum0 += __shfl_xor(sum0, 32);
  size_t sbase = (size_t)split * NN;
  if (l < 16) den_p[sbase + r0 + wv * 16 + l] = sum0;
  // C/D layout: col = l&15, row = kgrp*4 + i  (fp16 store)
#pragma unroll
  for (int cf = 0; cf < 8; ++cf) {
#pragma unroll
    for (int i = 0; i < 4; ++i) {
      int orow = r0 + wv * 16 + kgrp * 4 + i;
      int ocol = cf * 16 + l15;
      num_p[(sbase + orow) * (size_t)FO + ocol] = (_Float16)acc[cf][i];
    }
  }
}

// ---------------- K5: finalize out = elu(sum(num)/sum(den)) ----------------
__global__ void k5_fin(const _Float16* __restrict__ num_p,
                       const float* __restrict__ den_p, float* __restrict__ out) {
  int idx = blockIdx.x * 256 + threadIdx.x;
  int row = idx >> 7;
  float num = 0.f, den = 0.f;
#pragma unroll
  for (int s = 0; s < SPLITK; ++s) {
    num += (float)num_p[(size_t)s * (NN * FO) + idx];
    den += den_p[(size_t)s * NN + row];
  }
  float v = num / den;
  out[idx] = v > 0.f ? v : expm1f(v);
}

extern "C" void kernel_launch(void* const* d_in, const int* in_sizes, int n_in,
                              void* d_out, int out_size, void* d_ws, size_t ws_size,
                              hipStream_t stream) {
  const float* x   = (const float*)d_in[0];
  const int*   adj = (const int*)d_in[1];
  const float* W   = (const float*)d_in[2];
  const float* a   = (const float*)d_in[3];
  float* out = (float*)d_out;
  char* ws = (char*)d_ws;

  float*     h     = (float*)ws;                                   // 4 MB
  _Float16*  hT    = (_Float16*)(ws + ((size_t)4 << 20));          // 2 MB
  float*     s1    = (float*)(ws + ((size_t)6 << 20));             // 32 KB
  float*     s2    = (float*)(ws + ((size_t)6 << 20) + (32u << 10));
  unsigned*  enc   = (unsigned*)(ws + ((size_t)6 << 20) + (64u << 10));
  float*     den_p = (float*)(ws + ((size_t)6 << 20) + (128u << 10)); // 256 KB
  _Float16*  num_p = (_Float16*)(ws + ((size_t)7 << 20));          // 8 * 2 MB

  k1_xw<<<dim3(256), dim3(256), 0, stream>>>(x, W, h, enc);
  k2_prep<<<dim3(128), dim3(256), 0, stream>>>(h, a, hT, s1, s2, enc);
  k4_main<<<dim3(SPLITK, 128), dim3(256), 0, stream>>>(adj, s1, s2, enc, hT,
                                                       num_p, den_p);
  k5_fin<<<dim3((NN * FO) / 256), dim3(256), 0, stream>>>(num_p, den_p, out);
}

// Round 16
// 112.887 us; speedup vs baseline: 1.2575x; 1.2575x over previous
//
#include <hip/hip_runtime.h>
#include <hip/hip_bf16.h>
#include <cstdint>
#include <cstddef>

#define NN 8192
#define FIN 256
#define FO 128
#define SPLITK 8
#define JCH 1024   // NN / SPLITK; 16 bodies x 64 j; 4 windows x 256 j

typedef float f32x4 __attribute__((ext_vector_type(4)));
typedef _Float16 f16x8 __attribute__((ext_vector_type(8)));
typedef unsigned long long ull;

typedef __attribute__((address_space(3))) void lds_void;
typedef const __attribute__((address_space(1))) void glb_void;
__device__ __forceinline__ void gl_lds16(const void* g, void* l) {
  __builtin_amdgcn_global_load_lds((glb_void*)g, (lds_void*)l, 16, 0, 0);
}

__device__ __forceinline__ unsigned enc_f32(float f) {
  unsigned u = __float_as_uint(f);
  return (u & 0x80000000u) ? ~u : (u | 0x80000000u);
}
__device__ __forceinline__ float dec_f32(unsigned u) {
  unsigned b = (u & 0x80000000u) ? (u ^ 0x80000000u) : ~u;
  return __uint_as_float(b);
}

// ---------------- K1: h = x @ W  (8192x256 @ 256x128) ----------------
__global__ void k1_xw(const float* __restrict__ x, const float* __restrict__ W,
                      float* __restrict__ h, unsigned* __restrict__ enc) {
  __shared__ float xs[32 * 66];
  __shared__ float Ws[64 * 128];
  int t = threadIdx.x;
  int r0 = blockIdx.x * 32;
  if (blockIdx.x == 0 && t == 0) *enc = 0u;  // init for K2's atomicMax
  int r = t & 31, cg = t >> 5;
  float acc[16];
#pragma unroll
  for (int i = 0; i < 16; ++i) acc[i] = 0.f;
  for (int ko = 0; ko < 4; ++ko) {
    __syncthreads();
    {
      int rr = t >> 3, kc = (t & 7) * 8;
      const float2* src = (const float2*)(x + (size_t)(r0 + rr) * FIN + ko * 64 + kc);
      float2* dst = (float2*)&xs[rr * 66 + kc];
#pragma unroll
      for (int q = 0; q < 4; ++q) dst[q] = src[q];
    }
    {
      int kk = t >> 2, q = t & 3;
      const float4* src = (const float4*)(W + (size_t)(ko * 64 + kk) * FO + q * 32);
      float4* dst = (float4*)&Ws[kk * 128 + q * 32];
#pragma unroll
      for (int i = 0; i < 8; ++i) dst[i] = src[i];
    }
    __syncthreads();
#pragma unroll 8
    for (int kk = 0; kk < 64; ++kk) {
      float xv = xs[r * 66 + kk];
      const float4* wr = (const float4*)&Ws[kk * 128 + cg * 16];
      float4 w0 = wr[0], w1 = wr[1], w2 = wr[2], w3 = wr[3];
      acc[0]  = fmaf(xv, w0.x, acc[0]);  acc[1]  = fmaf(xv, w0.y, acc[1]);
      acc[2]  = fmaf(xv, w0.z, acc[2]);  acc[3]  = fmaf(xv, w0.w, acc[3]);
      acc[4]  = fmaf(xv, w1.x, acc[4]);  acc[5]  = fmaf(xv, w1.y, acc[5]);
      acc[6]  = fmaf(xv, w1.z, acc[6]);  acc[7]  = fmaf(xv, w1.w, acc[7]);
      acc[8]  = fmaf(xv, w2.x, acc[8]);  acc[9]  = fmaf(xv, w2.y, acc[9]);
      acc[10] = fmaf(xv, w2.z, acc[10]); acc[11] = fmaf(xv, w2.w, acc[11]);
      acc[12] = fmaf(xv, w3.x, acc[12]); acc[13] = fmaf(xv, w3.y, acc[13]);
      acc[14] = fmaf(xv, w3.z, acc[14]); acc[15] = fmaf(xv, w3.w, acc[15]);
    }
  }
  float* hp = h + (size_t)(r0 + r) * FO + cg * 16;
#pragma unroll
  for (int i = 0; i < 4; ++i)
    ((float4*)hp)[i] = make_float4(acc[4 * i], acc[4 * i + 1], acc[4 * i + 2], acc[4 * i + 3]);
}

// ---------------- K2: hT (fp16 transpose), s1, s2, max(s2) ----------------
__global__ void k2_prep(const float* __restrict__ h, const float* __restrict__ a,
                        _Float16* __restrict__ hT,
                        float* __restrict__ s1, float* __restrict__ s2,
                        unsigned* __restrict__ enc) {
  __shared__ float ht[64 * 129];
  int t = threadIdx.x;
  int r0 = blockIdx.x * 64;
  {
    int rr = t >> 2, q = t & 3;
    const float4* src = (const float4*)(h + (size_t)(r0 + rr) * FO + q * 32);
    float* dst = &ht[rr * 129 + q * 32];
#pragma unroll
    for (int i = 0; i < 8; ++i) {
      float4 v = src[i];
      dst[4 * i + 0] = v.x; dst[4 * i + 1] = v.y;
      dst[4 * i + 2] = v.z; dst[4 * i + 3] = v.w;
    }
  }
  __syncthreads();
  {
    int c = t >> 1, half = t & 1;
    alignas(16) _Float16 buf[32];
#pragma unroll
    for (int i = 0; i < 32; ++i) buf[i] = (_Float16)ht[(half * 32 + i) * 129 + c];
    int4* d = (int4*)(hT + (size_t)c * NN + r0 + half * 32);
#pragma unroll
    for (int i = 0; i < 4; ++i) d[i] = ((const int4*)buf)[i];
  }
  if (t < 64) {
    int row = r0 + t;
    float v1 = 0.f, v2 = 0.f;
#pragma unroll 16
    for (int c = 0; c < FO; ++c) {
      float hv = ht[t * 129 + c];
      v1 = fmaf(hv, a[c], v1);
      v2 = fmaf(hv, a[FO + c], v2);
    }
    s1[row] = v1; s2[row] = v2;
    float m = v2;
#pragma unroll
    for (int off = 1; off < 64; off <<= 1) m = fmaxf(m, __shfl_xor(m, off));
    if (t == 0) atomicMax(enc, enc_f32(m));
  }
}

// weight: w = bit ? exp(leaky(s1+s2) - m) : 0, rounded to fp16;
// den accumulates the *rounded* weight in f32 for exact normalization consistency.
__device__ __forceinline__ _Float16 wel(unsigned av, float s2v, float s1v, float mv, float& sum) {
  float tt = s1v + s2v;
  tt = fmaxf(tt, 0.01f * tt);  // leaky_relu
  float wf = av ? __expf(tt - mv) : 0.f;
  _Float16 wh = (_Float16)wf;
  sum += (float)wh;
  return wh;
}

// Load 4 rows (4P..4P+3) of a 256-col window: ONE int4/row = 1 KB contiguous
// per wave-instruction (page-burst: each 4KB row-page consumed in 4 sweeps).
#define LOAD4(SET, WIN, P)                                                       \
  _Pragma("unroll")                                                              \
  for (int rr = 0; rr < 4; ++rr)                                                 \
    SET[rr] = *(const int4*)(abase + (size_t)(4 * (P) + rr) * NN +               \
                             jbeg + (WIN) * 256);

// Ballot a loaded 4-row set into the window mask group (pre-shifted by kgrp*2).
// (bit plumbing hardware-verified: r13/r15 passed with this exact mapping)
#define BAL4(SET, P, M0, M1, M2, M3)                                             \
  _Pragma("unroll")                                                              \
  for (int rr = 0; rr < 4; ++rr) {                                               \
    ull b0 = __ballot(SET[rr].x > 0);                                            \
    ull b1 = __ballot(SET[rr].y > 0);                                            \
    ull b2 = __ballot(SET[rr].z > 0);                                            \
    ull b3 = __ballot(SET[rr].w > 0);                                            \
    bool sel = (l15 == 4 * (P) + rr);                                            \
    M0 = sel ? (b0 >> sh2) : M0;                                                 \
    M1 = sel ? (b1 >> sh2) : M1;                                                 \
    M2 = sel ? (b2 >> sh2) : M2;                                                 \
    M3 = sel ? (b3 >> sh2) : M3;                                                 \
  }

// One body (64 j): af[e] <-> word e&3, bit (T&3)*16 + ks*8 + e/4.
#define CONS(M0, M1, M2, M3, T)                                                  \
  {                                                                              \
    _Pragma("unroll")                                                            \
    for (int ks = 0; ks < 2; ++ks) {                                             \
      int SH = ((T) & 3) * 16 + ks * 8;                                          \
      unsigned c0 = (unsigned)((M0) >> SH);                                      \
      unsigned c1 = (unsigned)((M1) >> SH);                                      \
      unsigned c2 = (unsigned)((M2) >> SH);                                      \
      unsigned c3 = (unsigned)((M3) >> SH);                                      \
      int jloc = (T) * 64 + ks * 32 + kgrp * 8;                                  \
      f32x4 sa = *(const f32x4*)&s2l[jloc];                                      \
      f32x4 sb = *(const f32x4*)&s2l[jloc + 4];                                  \
      f16x8 af;                                                                  \
      af[0] = wel(c0 & 1u, sa[0], s10, mx0, sum0);                               \
      af[1] = wel(c1 & 1u, sa[1], s10, mx0, sum0);                               \
      af[2] = wel(c2 & 1u, sa[2], s10, mx0, sum0);                               \
      af[3] = wel(c3 & 1u, sa[3], s10, mx0, sum0);                               \
      af[4] = wel(c0 & 2u, sb[0], s10, mx0, sum0);                               \
      af[5] = wel(c1 & 2u, sb[1], s10, mx0, sum0);                               \
      af[6] = wel(c2 & 2u, sb[2], s10, mx0, sum0);                               \
      af[7] = wel(c3 & 2u, sb[3], s10, mx0, sum0);                               \
      _Pragma("unroll")                                                          \
      for (int cf = 0; cf < 8; ++cf) {                                           \
        f16x8 bfr = *(const f16x8*)&tile[(T) & 1][(cf * 16 + l15) * 64 +         \
                       ((ks * 32 + kgrp * 8) ^ (l7 * 8))];                       \
        acc[cf] = __builtin_amdgcn_mfma_f32_16x16x32_f16(af, bfr, acc[cf], 0, 0, 0); \
      }                                                                          \
    }                                                                            \
  }

// Body T: stage next tile; ballot S (set loaded at T-1; implicit vmcnt(4) wait
// keeps the just-issued stage in flight); reload S (same regs) for the next
// set; compute; end vmcnt(4) retires the stage (tile ready), keeps S.
#define BODY(T, DOB, PB, DOL, LW, LQ, C0, C1, C2, C3, B0, B1, B2, B3, VMS)       \
  {                                                                              \
    if ((T) < 15) stage(((T) + 1) & 1, jbeg + ((T) + 1) * 64);                   \
    if (DOB) { BAL4(S, PB, B0, B1, B2, B3) }                                     \
    if (DOL) { LOAD4(S, LW, LQ) }                                                \
    __builtin_amdgcn_sched_barrier(0);                                           \
    CONS(C0, C1, C2, C3, T)                                                      \
    __builtin_amdgcn_sched_barrier(0);                                           \
    if ((T) < 15) {                                                              \
      asm volatile("s_waitcnt vmcnt(" VMS ")" ::: "memory");                     \
      __builtin_amdgcn_s_barrier();                                              \
      __builtin_amdgcn_sched_barrier(0);                                         \
    }                                                                            \
  }

// ---------------- K4: fused attention x h, PAGE-BURST adj (single-S) ---------
// IDENTICAL to round-15 except __launch_bounds__(256, 3): raises the VGPR cap
// 128 -> 168 so the page-burst live-set (incl. CSE'd row addresses) fits
// without the 64-reg-tier spill collapse seen at (256,4). Occupancy 12 vs 16
// waves/CU; in-flight adj stays ample. Clean A/B on the spill.
__global__ void __launch_bounds__(256, 3) k4_main(
    const int* __restrict__ adj, const float* __restrict__ s1g,
    const float* __restrict__ s2g, const unsigned* __restrict__ enc,
    const _Float16* __restrict__ hT,
    _Float16* __restrict__ num_p, float* __restrict__ den_p) {
  __shared__ _Float16 tile[2][128 * 64];
  __shared__ float s2l[JCH];
  int t = threadIdx.x;
  int l = t & 63, wv = t >> 6;
  int l15 = l & 15, kgrp = l >> 4;
  int l7 = l15 & 7;
  int sh2 = kgrp * 2;
  int split = blockIdx.x;
  int r0 = blockIdx.y * 64;
  int jbeg = split * JCH;
  int row = r0 + wv * 16 + l15;

  float c2 = dec_f32(*enc);
  float s10 = s1g[row];
  float mx0 = s10 + c2; mx0 = fmaxf(mx0, 0.01f * mx0);

  f32x4 acc[8];
#pragma unroll
  for (int cf = 0; cf < 8; ++cf) acc[cf] = (f32x4){0.f, 0.f, 0.f, 0.f};
  float sum0 = 0.f;
  const int* abase = adj + (size_t)(r0 + wv * 16) * NN + 4 * l;  // lane's 16B slot

  auto stage = [&](int b, int jg) {
    const _Float16* g0 = hT + (size_t)(wv * 32 + (l >> 3)) * NN + jg +
                         (((l & 7) ^ (l >> 3)) * 8);
    _Float16* base = &tile[b][(wv * 32) * 64];
    gl_lds16(g0, base);
    gl_lds16(g0 + (size_t)8 * NN, base + 8 * 64);
    gl_lds16(g0 + (size_t)16 * NN, base + 16 * 64);
    gl_lds16(g0 + (size_t)24 * NN, base + 24 * 64);
  };

  int4 S[4];
  ull Ma0 = 0, Ma1 = 0, Ma2 = 0, Ma3 = 0;   // masks, even-parity window
  ull Mb0 = 0, Mb1 = 0, Mb2 = 0, Mb3 = 0;   // masks, odd-parity window

  // ---- prologue: s2 slice, tile0, window-0 masks (sequential), preload set0/win1
  *(float4*)&s2l[t * 4] = *(const float4*)(s2g + jbeg + t * 4);
  stage(0, jbeg);
  LOAD4(S, 0, 0) BAL4(S, 0, Ma0, Ma1, Ma2, Ma3)
  LOAD4(S, 0, 1) BAL4(S, 1, Ma0, Ma1, Ma2, Ma3)
  LOAD4(S, 0, 2) BAL4(S, 2, Ma0, Ma1, Ma2, Ma3)
  LOAD4(S, 0, 3) BAL4(S, 3, Ma0, Ma1, Ma2, Ma3)
  LOAD4(S, 1, 0)
  asm volatile("s_waitcnt vmcnt(4) lgkmcnt(0)" ::: "memory");
  __builtin_amdgcn_s_barrier();
  __builtin_amdgcn_sched_barrier(0);

  // ---- 16 bodies, fully static. window w consumed at bodies 4w..4w+3;
  //      set q of window w+1 balloted at body 4w+q (loaded one body earlier).
  BODY(0,  1, 0, 1, 1, 1, Ma0, Ma1, Ma2, Ma3, Mb0, Mb1, Mb2, Mb3, "4")
  BODY(1,  1, 1, 1, 1, 2, Ma0, Ma1, Ma2, Ma3, Mb0, Mb1, Mb2, Mb3, "4")
  BODY(2,  1, 2, 1, 1, 3, Ma0, Ma1, Ma2, Ma3, Mb0, Mb1, Mb2, Mb3, "4")
  BODY(3,  1, 3, 1, 2, 0, Ma0, Ma1, Ma2, Ma3, Mb0, Mb1, Mb2, Mb3, "4")
  BODY(4,  1, 0, 1, 2, 1, Mb0, Mb1, Mb2, Mb3, Ma0, Ma1, Ma2, Ma3, "4")
  BODY(5,  1, 1, 1, 2, 2, Mb0, Mb1, Mb2, Mb3, Ma0, Ma1, Ma2, Ma3, "4")
  BODY(6,  1, 2, 1, 2, 3, Mb0, Mb1, Mb2, Mb3, Ma0, Ma1, Ma2, Ma3, "4")
  BODY(7,  1, 3, 1, 3, 0, Mb0, Mb1, Mb2, Mb3, Ma0, Ma1, Ma2, Ma3, "4")
  BODY(8,  1, 0, 1, 3, 1, Ma0, Ma1, Ma2, Ma3, Mb0, Mb1, Mb2, Mb3, "4")
  BODY(9,  1, 1, 1, 3, 2, Ma0, Ma1, Ma2, Ma3, Mb0, Mb1, Mb2, Mb3, "4")
  BODY(10, 1, 2, 1, 3, 3, Ma0, Ma1, Ma2, Ma3, Mb0, Mb1, Mb2, Mb3, "4")
  BODY(11, 1, 3, 0, 3, 0, Ma0, Ma1, Ma2, Ma3, Mb0, Mb1, Mb2, Mb3, "0")
  BODY(12, 0, 0, 0, 3, 0, Mb0, Mb1, Mb2, Mb3, Ma0, Ma1, Ma2, Ma3, "0")
  BODY(13, 0, 0, 0, 3, 0, Mb0, Mb1, Mb2, Mb3, Ma0, Ma1, Ma2, Ma3, "0")
  BODY(14, 0, 0, 0, 3, 0, Mb0, Mb1, Mb2, Mb3, Ma0, Ma1, Ma2, Ma3, "0")
  BODY(15, 0, 0, 0, 3, 0, Mb0, Mb1, Mb2, Mb3, Ma0, Ma1, Ma2, Ma3, "0")

  // row sums: lanes kgrp 0..3 of same l15 combine
  sum0 += __shfl_xor(sum0, 16);
  sum0 += __shfl_xor(sum0, 32);
  size_t sbase = (size_t)split * NN;
  if (l < 16) den_p[sbase + r0 + wv * 16 + l] = sum0;
  // C/D layout: col = l&15, row = kgrp*4 + i  (fp16 store)
#pragma unroll
  for (int cf = 0; cf < 8; ++cf) {
#pragma unroll
    for (int i = 0; i < 4; ++i) {
      int orow = r0 + wv * 16 + kgrp * 4 + i;
      int ocol = cf * 16 + l15;
      num_p[(sbase + orow) * (size_t)FO + ocol] = (_Float16)acc[cf][i];
    }
  }
}

// ---------------- K5: finalize out = elu(sum(num)/sum(den)) ----------------
__global__ void k5_fin(const _Float16* __restrict__ num_p,
                       const float* __restrict__ den_p, float* __restrict__ out) {
  int idx = blockIdx.x * 256 + threadIdx.x;
  int row = idx >> 7;
  float num = 0.f, den = 0.f;
#pragma unroll
  for (int s = 0; s < SPLITK; ++s) {
    num += (float)num_p[(size_t)s * (NN * FO) + idx];
    den += den_p[(size_t)s * NN + row];
  }
  float v = num / den;
  out[idx] = v > 0.f ? v : expm1f(v);
}

extern "C" void kernel_launch(void* const* d_in, const int* in_sizes, int n_in,
                              void* d_out, int out_size, void* d_ws, size_t ws_size,
                              hipStream_t stream) {
  const float* x   = (const float*)d_in[0];
  const int*   adj = (const int*)d_in[1];
  const float* W   = (const float*)d_in[2];
  const float* a   = (const float*)d_in[3];
  float* out = (float*)d_out;
  char* ws = (char*)d_ws;

  float*     h     = (float*)ws;                                   // 4 MB
  _Float16*  hT    = (_Float16*)(ws + ((size_t)4 << 20));          // 2 MB
  float*     s1    = (float*)(ws + ((size_t)6 << 20));             // 32 KB
  float*     s2    = (float*)(ws + ((size_t)6 << 20) + (32u << 10));
  unsigned*  enc   = (unsigned*)(ws + ((size_t)6 << 20) + (64u << 10));
  float*     den_p = (float*)(ws + ((size_t)6 << 20) + (128u << 10)); // 256 KB
  _Float16*  num_p = (_Float16*)(ws + ((size_t)7 << 20));          // 8 * 2 MB

  k1_xw<<<dim3(256), dim3(256), 0, stream>>>(x, W, h, enc);
  k2_prep<<<dim3(128), dim3(256), 0, stream>>>(h, a, hT, s1, s2, enc);
  k4_main<<<dim3(SPLITK, 128), dim3(256), 0, stream>>>(adj, s1, s2, enc, hT,
                                                       num_p, den_p);
  k5_fin<<<dim3((NN * FO) / 256), dim3(256), 0, stream>>>(num_p, den_p, out);
}

// Round 17
// 102.449 us; speedup vs baseline: 1.3856x; 1.1019x over previous
//
#include <hip/hip_runtime.h>
#include <hip/hip_bf16.h>
#include <cstdint>
#include <cstddef>

#define NN 8192
#define FIN 256
#define FO 128
#define SPLITK 8
#define JCH 1024   // NN / SPLITK
#define NIT 16     // JCH / 64

typedef float f32x4 __attribute__((ext_vector_type(4)));
typedef _Float16 f16x8 __attribute__((ext_vector_type(8)));

typedef __attribute__((address_space(3))) void lds_void;
typedef const __attribute__((address_space(1))) void glb_void;
__device__ __forceinline__ void gl_lds16(const void* g, void* l) {
  __builtin_amdgcn_global_load_lds((glb_void*)g, (lds_void*)l, 16, 0, 0);
}

__device__ __forceinline__ unsigned enc_f32(float f) {
  unsigned u = __float_as_uint(f);
  return (u & 0x80000000u) ? ~u : (u | 0x80000000u);
}
__device__ __forceinline__ float dec_f32(unsigned u) {
  unsigned b = (u & 0x80000000u) ? (u ^ 0x80000000u) : ~u;
  return __uint_as_float(b);
}

// ---------------- K1: h = x @ W  (8192x256 @ 256x128) ----------------
__global__ void k1_xw(const float* __restrict__ x, const float* __restrict__ W,
                      float* __restrict__ h, unsigned* __restrict__ enc) {
  __shared__ float xs[32 * 66];
  __shared__ float Ws[64 * 128];
  int t = threadIdx.x;
  int r0 = blockIdx.x * 32;
  if (blockIdx.x == 0 && t == 0) *enc = 0u;  // init for K2's atomicMax
  int r = t & 31, cg = t >> 5;
  float acc[16];
#pragma unroll
  for (int i = 0; i < 16; ++i) acc[i] = 0.f;
  for (int ko = 0; ko < 4; ++ko) {
    __syncthreads();
    {
      int rr = t >> 3, kc = (t & 7) * 8;
      const float2* src = (const float2*)(x + (size_t)(r0 + rr) * FIN + ko * 64 + kc);
      float2* dst = (float2*)&xs[rr * 66 + kc];
#pragma unroll
      for (int q = 0; q < 4; ++q) dst[q] = src[q];
    }
    {
      int kk = t >> 2, q = t & 3;
      const float4* src = (const float4*)(W + (size_t)(ko * 64 + kk) * FO + q * 32);
      float4* dst = (float4*)&Ws[kk * 128 + q * 32];
#pragma unroll
      for (int i = 0; i < 8; ++i) dst[i] = src[i];
    }
    __syncthreads();
#pragma unroll 8
    for (int kk = 0; kk < 64; ++kk) {
      float xv = xs[r * 66 + kk];
      const float4* wr = (const float4*)&Ws[kk * 128 + cg * 16];
      float4 w0 = wr[0], w1 = wr[1], w2 = wr[2], w3 = wr[3];
      acc[0]  = fmaf(xv, w0.x, acc[0]);  acc[1]  = fmaf(xv, w0.y, acc[1]);
      acc[2]  = fmaf(xv, w0.z, acc[2]);  acc[3]  = fmaf(xv, w0.w, acc[3]);
      acc[4]  = fmaf(xv, w1.x, acc[4]);  acc[5]  = fmaf(xv, w1.y, acc[5]);
      acc[6]  = fmaf(xv, w1.z, acc[6]);  acc[7]  = fmaf(xv, w1.w, acc[7]);
      acc[8]  = fmaf(xv, w2.x, acc[8]);  acc[9]  = fmaf(xv, w2.y, acc[9]);
      acc[10] = fmaf(xv, w2.z, acc[10]); acc[11] = fmaf(xv, w2.w, acc[11]);
      acc[12] = fmaf(xv, w3.x, acc[12]); acc[13] = fmaf(xv, w3.y, acc[13]);
      acc[14] = fmaf(xv, w3.z, acc[14]); acc[15] = fmaf(xv, w3.w, acc[15]);
    }
  }
  float* hp = h + (size_t)(r0 + r) * FO + cg * 16;
#pragma unroll
  for (int i = 0; i < 4; ++i)
    ((float4*)hp)[i] = make_float4(acc[4 * i], acc[4 * i + 1], acc[4 * i + 2], acc[4 * i + 3]);
}

// ---------------- K2: hT (fp16 transpose), s1, s2, max(s2) ----------------
__global__ void k2_prep(const float* __restrict__ h, const float* __restrict__ a,
                        _Float16* __restrict__ hT,
                        float* __restrict__ s1, float* __restrict__ s2,
                        unsigned* __restrict__ enc) {
  __shared__ float ht[64 * 129];
  int t = threadIdx.x;
  int r0 = blockIdx.x * 64;
  {
    int rr = t >> 2, q = t & 3;
    const float4* src = (const float4*)(h + (size_t)(r0 + rr) * FO + q * 32);
    float* dst = &ht[rr * 129 + q * 32];
#pragma unroll
    for (int i = 0; i < 8; ++i) {
      float4 v = src[i];
      dst[4 * i + 0] = v.x; dst[4 * i + 1] = v.y;
      dst[4 * i + 2] = v.z; dst[4 * i + 3] = v.w;
    }
  }
  __syncthreads();
  {
    int c = t >> 1, half = t & 1;
    alignas(16) _Float16 buf[32];
#pragma unroll
    for (int i = 0; i < 32; ++i) buf[i] = (_Float16)ht[(half * 32 + i) * 129 + c];
    int4* d = (int4*)(hT + (size_t)c * NN + r0 + half * 32);
#pragma unroll
    for (int i = 0; i < 4; ++i) d[i] = ((const int4*)buf)[i];
  }
  if (t < 64) {
    int row = r0 + t;
    float v1 = 0.f, v2 = 0.f;
#pragma unroll 16
    for (int c = 0; c < FO; ++c) {
      float hv = ht[t * 129 + c];
      v1 = fmaf(hv, a[c], v1);
      v2 = fmaf(hv, a[FO + c], v2);
    }
    s1[row] = v1; s2[row] = v2;
    float m = v2;
#pragma unroll
    for (int off = 1; off < 64; off <<= 1) m = fmaxf(m, __shfl_xor(m, off));
    if (t == 0) atomicMax(enc, enc_f32(m));
  }
}

// weight: w = bit ? exp(leaky(s1+s2) - m) : 0, rounded to fp16;
// den accumulates the *rounded* weight in f32 for exact normalization consistency.
__device__ __forceinline__ _Float16 wel(unsigned av, float s2v, float s1v, float mv, float& sum) {
  float tt = s1v + s2v;
  tt = fmaxf(tt, 0.01f * tt);  // leaky_relu
  float wf = av ? __expf(tt - mv) : 0.f;
  _Float16 wh = (_Float16)wf;
  sum += (float)wh;
  return wh;
}

#define LOADSET(S, J)                                                            \
  _Pragma("unroll")                                                              \
  for (int rr = 0; rr < 16; ++rr) S[rr] = abase[(size_t)rr * NN + (J)];

// One j-step of 64 cols. CR: current adj regs; NR: next adj regs (filled if PF).
// BUF: current tile buffer. All indices static (macro-expanded, rule #20).
#define K4BODY(CR, NR, BUF, JC, PF, LAST)                                        \
  {                                                                              \
    if (PF) {                                                                    \
      stage(BUF ^ 1, (JC) + 64);                                                 \
      _Pragma("unroll")                                                          \
      for (int rr = 0; rr < 16; ++rr)                                            \
        NR[rr] = abase[(size_t)rr * NN + (JC) + 64];                             \
    }                                                                            \
    __builtin_amdgcn_sched_barrier(0);                                           \
    unsigned mlo = 0u, mhi = 0u;                                                 \
    _Pragma("unroll")                                                            \
    for (int rr = 0; rr < 16; ++rr) {                                            \
      unsigned long long br = __ballot(CR[rr] > 0);                              \
      bool sel = (l15 == rr);                                                    \
      mlo = sel ? (unsigned)br : mlo;                                            \
      mhi = sel ? (unsigned)(br >> 32) : mhi;                                    \
    }                                                                            \
    _Pragma("unroll")                                                            \
    for (int ks = 0; ks < 2; ++ks) {                                             \
      unsigned mm = ks ? mhi : mlo;                                              \
      unsigned byt = (mm >> (kgrp << 3)) & 0xffu;                                \
      int jloc = ((JC) - jbeg) + ks * 32 + kgrp * 8;                             \
      f32x4 sa = *(const f32x4*)&s2l[jloc];                                      \
      f32x4 sb = *(const f32x4*)&s2l[jloc + 4];                                  \
      f16x8 af;                                                                  \
      af[0] = wel(byt & 1u,   sa[0], s10, m0, sum0);                             \
      af[1] = wel(byt & 2u,   sa[1], s10, m0, sum0);                             \
      af[2] = wel(byt & 4u,   sa[2], s10, m0, sum0);                             \
      af[3] = wel(byt & 8u,   sa[3], s10, m0, sum0);                             \
      af[4] = wel(byt & 16u,  sb[0], s10, m0, sum0);                             \
      af[5] = wel(byt & 32u,  sb[1], s10, m0, sum0);                             \
      af[6] = wel(byt & 64u,  sb[2], s10, m0, sum0);                             \
      af[7] = wel(byt & 128u, sb[3], s10, m0, sum0);                             \
      _Pragma("unroll")                                                          \
      for (int cf = 0; cf < 8; ++cf) {                                           \
        f16x8 bfr = *(const f16x8*)&tile[BUF][(cf * 16 + l15) * 64 +             \
                       ((ks * 32 + kgrp * 8) ^ (l7 * 8))];                       \
        acc[cf] = __builtin_amdgcn_mfma_f32_16x16x32_f16(af, bfr, acc[cf], 0, 0, 0); \
      }                                                                          \
    }                                                                            \
    __builtin_amdgcn_sched_barrier(0);                                           \
    if (!(LAST)) {                                                               \
      asm volatile("s_waitcnt vmcnt(16)" ::: "memory");                          \
      __builtin_amdgcn_s_barrier();                                              \
      __builtin_amdgcn_sched_barrier(0);                                         \
    }                                                                            \
  }

// ---------------- K4: fully fused attention x h, adj read STREAMING ----------
// grid (SPLITK=8 splits, 128 row-blocks), 256 threads = 4 waves x 16 rows.
// Each wave reads its 16 adj rows as 16x (1 row x 256 B contiguous) instructions,
// __ballot -> row masks, cndmask routes mask[l15] into fragment layout.
// hT tile [128][64] fp16 double-buffered via global_load_lds with BOTH-SIDES
// XOR swizzle (slot ^= row&7): pre-swizzled global src + swizzled ds_read.
// s2 split-slice staged once to LDS (no VMEM in body except stage+adj).
// (Verified 102.6 us configuration — the session optimum.)
__global__ void __launch_bounds__(256, 4) k4_main(
    const int* __restrict__ adj, const float* __restrict__ s1g,
    const float* __restrict__ s2g, const unsigned* __restrict__ enc,
    const _Float16* __restrict__ hT,
    _Float16* __restrict__ num_p, float* __restrict__ den_p) {
  __shared__ _Float16 tile[2][128 * 64];
  __shared__ float s2l[JCH];
  int t = threadIdx.x;
  int l = t & 63, wv = t >> 6;
  int l15 = l & 15, kgrp = l >> 4;
  int l7 = l15 & 7;
  int split = blockIdx.x;
  int r0 = blockIdx.y * 64;
  int jbeg = split * JCH;
  int row = r0 + wv * 16 + l15;

  float c2 = dec_f32(*enc);
  float s10 = s1g[row];
  float m0 = s10 + c2; m0 = fmaxf(m0, 0.01f * m0);

  f32x4 acc[8];
#pragma unroll
  for (int cf = 0; cf < 8; ++cf) acc[cf] = (f32x4){0.f, 0.f, 0.f, 0.f};
  float sum0 = 0.f;
  const int* abase = adj + (size_t)(r0 + wv * 16) * NN + l;  // wave's row 0, col l

  // stage [128][64] tile, wave wv covers rows wv*32..+31; linear LDS dest,
  // global col slot pre-XOR'd with row&7 (= l>>3, invariant across +8k rows).
  auto stage = [&](int b, int jg) {
    const _Float16* g0 = hT + (size_t)(wv * 32 + (l >> 3)) * NN + jg +
                         (((l & 7) ^ (l >> 3)) * 8);
    _Float16* base = &tile[b][(wv * 32) * 64];
    gl_lds16(g0, base);
    gl_lds16(g0 + (size_t)8 * NN, base + 8 * 64);
    gl_lds16(g0 + (size_t)16 * NN, base + 16 * 64);
    gl_lds16(g0 + (size_t)24 * NN, base + 24 * 64);
  };

  // ---- prologue: stage buf0, s2 slice -> LDS, iter0 adj ----
  int ra[16], rb[16];
  stage(0, jbeg);
  *(float4*)&s2l[t * 4] = *(const float4*)(s2g + jbeg + t * 4);
#pragma unroll
  for (int rr = 0; rr < 16; ++rr) ra[rr] = abase[(size_t)rr * NN + jbeg];
  __syncthreads();

#pragma unroll 1
  for (int tI = 0; tI < NIT; tI += 2) {
    int jc = jbeg + tI * 64;
    K4BODY(ra, rb, 0, jc, true, false);
    K4BODY(rb, ra, 1, jc + 64, (tI + 2 < NIT), (tI + 2 >= NIT));
  }

  // row sums: lanes kgrp 0..3 of same l15 combine
  sum0 += __shfl_xor(sum0, 16);
  sum0 += __shfl_xor(sum0, 32);
  size_t sbase = (size_t)split * NN;
  if (l < 16) den_p[sbase + r0 + wv * 16 + l] = sum0;
  // C/D layout: col = l&15, row = kgrp*4 + i  (fp16 store: halves k4/k5 traffic)
#pragma unroll
  for (int cf = 0; cf < 8; ++cf) {
#pragma unroll
    for (int i = 0; i < 4; ++i) {
      int orow = r0 + wv * 16 + kgrp * 4 + i;
      int ocol = cf * 16 + l15;
      num_p[(sbase + orow) * (size_t)FO + ocol] = (_Float16)acc[cf][i];
    }
  }
}

// ---------------- K5: finalize out = elu(sum(num)/sum(den)) ----------------
__global__ void k5_fin(const _Float16* __restrict__ num_p,
                       const float* __restrict__ den_p, float* __restrict__ out) {
  int idx = blockIdx.x * 256 + threadIdx.x;
  int row = idx >> 7;
  float num = 0.f, den = 0.f;
#pragma unroll
  for (int s = 0; s < SPLITK; ++s) {
    num += (float)num_p[(size_t)s * (NN * FO) + idx];
    den += den_p[(size_t)s * NN + row];
  }
  float v = num / den;
  out[idx] = v > 0.f ? v : expm1f(v);
}

extern "C" void kernel_launch(void* const* d_in, const int* in_sizes, int n_in,
                              void* d_out, int out_size, void* d_ws, size_t ws_size,
                              hipStream_t stream) {
  const float* x   = (const float*)d_in[0];
  const int*   adj = (const int*)d_in[1];
  const float* W   = (const float*)d_in[2];
  const float* a   = (const float*)d_in[3];
  float* out = (float*)d_out;
  char* ws = (char*)d_ws;

  float*     h     = (float*)ws;                                   // 4 MB
  _Float16*  hT    = (_Float16*)(ws + ((size_t)4 << 20));          // 2 MB
  float*     s1    = (float*)(ws + ((size_t)6 << 20));             // 32 KB
  float*     s2    = (float*)(ws + ((size_t)6 << 20) + (32u << 10));
  unsigned*  enc   = (unsigned*)(ws + ((size_t)6 << 20) + (64u << 10));
  float*     den_p = (float*)(ws + ((size_t)6 << 20) + (128u << 10)); // 256 KB
  _Float16*  num_p = (_Float16*)(ws + ((size_t)7 << 20));          // 8 * 2 MB

  k1_xw<<<dim3(256), dim3(256), 0, stream>>>(x, W, h, enc);
  k2_prep<<<dim3(128), dim3(256), 0, stream>>>(h, a, hT, s1, s2, enc);
  k4_main<<<dim3(SPLITK, 128), dim3(256), 0, stream>>>(adj, s1, s2, enc, hT,
                                                       num_p, den_p);
  k5_fin<<<dim3((NN * FO) / 256), dim3(256), 0, stream>>>(num_p, den_p, out);
}